// Round 8
// baseline (138.295 us; speedup 1.0000x reference)
//
#include <hip/hip_runtime.h>
#include <stdint.h>

// Problem constants (fixed by reference: R=C=256, S=32, B=64)
#define N_NEUR  65536
#define NNZ_E   2162688          // N * 33
#define NBUK    4096             // buckets of 16 destination rows
#define BSH     4                // bucket = row >> 4
#define BROWS   16
#define EPB     4096             // edges per bin block (528 blocks exactly)
#define NBLK_E  (NNZ_E / EPB)    // 528
#define CAP     4096             // max entries per bucket (analytic worst ~3000)

// Workspace layout (bytes):
//   xt     @ 0         : N*64*4 = 16,777,216    x transposed [N][64]
//   bcnt   @ 16777216  : 4096*4   (true counts)
//   boffs  @ 16793600  : 4096*4   (even-padded exclusive scan)
//   gcur   @ 16809984  : 4096*4
//   csr1   @ 16826368  : (NNZ+4096)*8   = 17,334,272   bucket-sorted
//   csr2   @ 34160640  : (NNZ+4096*17)*8 = 17,858,560  fully row-sorted, even-padded
//   rowoff @ 52019200  : 65536*4
//   rowcnt @ 52281344  : 65536*4          (total ~52.5 MB)

// ---------------- K1: fused transpose (blocks 0..1023) + bucket hist (rest) ----
__global__ __launch_bounds__(256) void k_front(const float* __restrict__ x,
                                               float* __restrict__ xt,
                                               const int* __restrict__ rows,
                                               int* __restrict__ bcnt) {
  __shared__ float smem[64 * 65];            // union: transpose tile / hist counters
  const int t = threadIdx.x;
  if (blockIdx.x < 1024) {
    float (*tile)[65] = (float (*)[65])smem;
    const int n0 = blockIdx.x * 64;
    const int lane = t & 63;
    const int w = t >> 6;
    #pragma unroll
    for (int bb = w; bb < 64; bb += 4)
      tile[bb][lane] = x[(size_t)bb * N_NEUR + n0 + lane];
    __syncthreads();
    #pragma unroll
    for (int nn = w; nn < 64; nn += 4)
      xt[(size_t)(n0 + nn) * 64 + lane] = tile[lane][nn];
  } else {
    int* lh = (int*)smem;                    // 4096 counters
    #pragma unroll
    for (int q = 0; q < NBUK / 256; ++q) lh[q * 256 + t] = 0;
    __syncthreads();
    const int e0 = (blockIdx.x - 1024) * EPB;
    #pragma unroll
    for (int k = 0; k < EPB / 256; ++k)
      atomicAdd(&lh[rows[e0 + k * 256 + t] >> BSH], 1);
    __syncthreads();
    #pragma unroll
    for (int q = 0; q < NBUK / 256; ++q) {
      const int v = lh[q * 256 + t];
      if (v) atomicAdd(&bcnt[q * 256 + t], v);
    }
  }
}

// ---------------- K2: even-padded exclusive scan over 4096 bucket counts --------
__device__ inline int wave_incl_scan(int v, int lane) {
  #pragma unroll
  for (int off = 1; off < 64; off <<= 1) {
    int tv = __shfl_up(v, off, 64);
    if (lane >= off) v += tv;
  }
  return v;
}

__global__ __launch_bounds__(256) void k_bscan(const int* __restrict__ bcnt,
                                               int* __restrict__ boffs,
                                               int* __restrict__ gcur) {
  const int t = threadIdx.x, lane = t & 63, w = t >> 6;
  int c[16], s = 0;
  #pragma unroll
  for (int k = 0; k < 16; ++k) {
    c[k] = (bcnt[t * 16 + k] + 1) & ~1;   // round each bucket to even
    s += c[k];
  }
  int incl = wave_incl_scan(s, lane);
  __shared__ int wsum[4];
  if (lane == 63) wsum[w] = incl;
  __syncthreads();
  int base = 0;
  for (int i = 0; i < w; ++i) base += wsum[i];
  int run = base + incl - s;
  #pragma unroll
  for (int k = 0; k < 16; ++k) {
    boffs[t * 16 + k] = run;     // even for every bucket
    gcur[t * 16 + k]  = run;
    run += c[k];
  }
}

// ---------------- K3: bucket-bin edges with coalesced chunk writes ----------------
// lc doubles as sbase after the reservation phase
__global__ __launch_bounds__(256) void k_bin(const int* __restrict__ rows,
                                             const float* __restrict__ vals,
                                             int* __restrict__ gcur,
                                             uint64_t* __restrict__ csr1) {
  __shared__ int lc[NBUK];        // 16 KB  (count, then sbase)
  __shared__ int lofs[NBUK];      // 16 KB  (scan, then cursor)
  __shared__ int wsum[4];
  __shared__ uint64_t ebuf[EPB];  // 32 KB
  const int t = threadIdx.x, lane = t & 63, w = t >> 6;
  #pragma unroll
  for (int q = 0; q < NBUK / 256; ++q) lc[q * 256 + t] = 0;
  __syncthreads();
  const int e0 = blockIdx.x * EPB;
  int rcache[EPB / 256];
  #pragma unroll
  for (int k = 0; k < EPB / 256; ++k) {
    const int r = rows[e0 + k * 256 + t];
    rcache[k] = r;
    atomicAdd(&lc[r >> BSH], 1);
  }
  __syncthreads();
  {  // exclusive scan lc[4096] -> lofs (thread-chunked 16)
    int c[16], s = 0;
    #pragma unroll
    for (int k = 0; k < 16; ++k) { c[k] = lc[t * 16 + k]; s += c[k]; }
    int incl = wave_incl_scan(s, lane);
    if (lane == 63) wsum[w] = incl;
    __syncthreads();
    int base = 0;
    for (int i = 0; i < w; ++i) base += wsum[i];
    int run = base + incl - s;
    #pragma unroll
    for (int k = 0; k < 16; ++k) { lofs[t * 16 + k] = run; run += c[k]; }
  }
  __syncthreads();
  // reserve contiguous global chunk per non-empty bucket; lc[bb] := sbase
  #pragma unroll
  for (int q = 0; q < NBUK / 256; ++q) {
    const int bb = q * 256 + t;
    const int c = lc[bb];
    if (c) lc[bb] = atomicAdd(&gcur[bb], c) - lofs[bb];
  }
  __syncthreads();
  // local bucket-sort into ebuf (lofs doubles as cursor)
  #pragma unroll
  for (int k = 0; k < EPB / 256; ++k) {
    const int e = e0 + k * 256 + t;
    const int r = rcache[k];
    const uint32_t c = (uint32_t)e / 33u;      // cols[e] == e / 33 structurally
    const uint64_t pk = ((uint64_t)__float_as_uint(vals[e]) << 32) |
                        ((uint32_t)r << 16) | c;
    const int pos = atomicAdd(&lofs[r >> BSH], 1);
    ebuf[pos] = pk;
  }
  __syncthreads();
  // coalesced write-out: same-bucket runs -> consecutive global targets
  #pragma unroll
  for (int k = 0; k < EPB / 256; ++k) {
    const int idx = k * 256 + t;
    const uint64_t pk = ebuf[idx];
    const int bb = (int)((pk >> (16 + BSH)) & (NBUK - 1));
    csr1[lc[bb] + idx] = pk;
  }
}

// ---------------- K4: per-bucket full row-sort, even-padded -> csr2 + rowoff/cnt --
__global__ __launch_bounds__(256) void k_bin2(const int* __restrict__ bcnt,
                                              const int* __restrict__ boffs,
                                              const uint64_t* __restrict__ csr1,
                                              uint64_t* __restrict__ csr2,
                                              int* __restrict__ rowoff,
                                              int* __restrict__ rowcnt) {
  __shared__ uint64_t ebuf[CAP + BROWS];   // 32.1 KB
  __shared__ int lh[BROWS], lofs[BROWS], lcur[BROWS], lpc[BROWS];
  __shared__ int ptot_s;
  const int t = threadIdx.x;
  const int g = blockIdx.x;
  const int beg = boffs[g];
  int cnt = bcnt[g];
  if (cnt > CAP) cnt = CAP;   // safety clamp
  if (t < BROWS) lh[t] = 0;
  __syncthreads();
  // stage to regs + row histogram
  uint64_t E[CAP / 256];
  #pragma unroll
  for (int u = 0; u < CAP / 256; ++u) {
    const int i = u * 256 + t;
    if (i < cnt) {
      const uint64_t e = csr1[beg + i];
      E[u] = e;
      atomicAdd(&lh[(int)((e >> 16) & (BROWS - 1))], 1);
    }
  }
  __syncthreads();
  if (t == 0) {
    int run = 0;
    #pragma unroll
    for (int r = 0; r < BROWS; ++r) {
      const int c = lh[r];
      const int pc = (c + 1) & ~1;        // even-pad each row
      lofs[r] = run; lcur[r] = run; lpc[r] = pc;
      run += pc;
    }
    ptot_s = run;
  }
  __syncthreads();
  // fill pad slots with (val=0, col=0): exact no-op edges
  if (t < BROWS && (lh[t] & 1)) ebuf[lofs[t] + lh[t]] = 0ULL;
  // scatter into row-sorted order
  #pragma unroll
  for (int u = 0; u < CAP / 256; ++u) {
    const int i = u * 256 + t;
    if (i < cnt) {
      const int rlo = (int)((E[u] >> 16) & (BROWS - 1));
      const int pos = atomicAdd(&lcur[rlo], 1);
      ebuf[pos] = E[u];
    }
  }
  __syncthreads();
  const int base2 = beg + g * BROWS;   // per-bucket +16 reserve; even
  const int ptot = ptot_s;
  for (int i = t; i < ptot; i += 256)
    csr2[base2 + i] = ebuf[i];         // coalesced
  if (t < BROWS) {
    rowoff[g * BROWS + t] = base2 + lofs[t];
    rowcnt[g * BROWS + t] = lpc[t];
  }
}

// ---------------- K5: lean gather — uniform 16B edge-pair stream, reg acc --------
__global__ __launch_bounds__(256) void k_gather(const float* __restrict__ xt,
                                                const int* __restrict__ rowoff,
                                                const int* __restrict__ rowcnt,
                                                const uint64_t* __restrict__ csr2,
                                                float* __restrict__ out) {
  __shared__ float tile[BROWS][66];
  const int t = threadIdx.x, lane = t & 63, w = t >> 6;
  const int bid = blockIdx.x;
  const int g = (bid & 7) * (NBUK / 8) + (bid >> 3);   // XCD-chunked swizzle
  const int r0 = g * BROWS;
  #pragma unroll
  for (int q = 0; q < 4; ++q) {
    const int r = r0 + w * 4 + q;
    const int s  = __builtin_amdgcn_readfirstlane(rowoff[r]);   // even
    const int n2 = __builtin_amdgcn_readfirstlane(rowcnt[r]) >> 1;
    const ulonglong2* __restrict__ ep2 = (const ulonglong2*)csr2 + (s >> 1);
    float a0 = 0.f, a1 = 0.f, a2 = 0.f, a3 = 0.f;
    int k = 0;
    for (; k + 4 <= n2; k += 4) {   // 8 edges in flight
      const ulonglong2 q0 = ep2[k], q1 = ep2[k+1], q2 = ep2[k+2], q3 = ep2[k+3];
      const float p0 = xt[(int)(q0.x & 0xFFFF) * 64 + lane];
      const float p1 = xt[(int)(q0.y & 0xFFFF) * 64 + lane];
      const float p2 = xt[(int)(q1.x & 0xFFFF) * 64 + lane];
      const float p3 = xt[(int)(q1.y & 0xFFFF) * 64 + lane];
      const float p4 = xt[(int)(q2.x & 0xFFFF) * 64 + lane];
      const float p5 = xt[(int)(q2.y & 0xFFFF) * 64 + lane];
      const float p6 = xt[(int)(q3.x & 0xFFFF) * 64 + lane];
      const float p7 = xt[(int)(q3.y & 0xFFFF) * 64 + lane];
      a0 = fmaf(__uint_as_float((uint32_t)(q0.x >> 32)), p0, a0);
      a1 = fmaf(__uint_as_float((uint32_t)(q0.y >> 32)), p1, a1);
      a2 = fmaf(__uint_as_float((uint32_t)(q1.x >> 32)), p2, a2);
      a3 = fmaf(__uint_as_float((uint32_t)(q1.y >> 32)), p3, a3);
      a0 = fmaf(__uint_as_float((uint32_t)(q2.x >> 32)), p4, a0);
      a1 = fmaf(__uint_as_float((uint32_t)(q2.y >> 32)), p5, a1);
      a2 = fmaf(__uint_as_float((uint32_t)(q3.x >> 32)), p6, a2);
      a3 = fmaf(__uint_as_float((uint32_t)(q3.y >> 32)), p7, a3);
    }
    for (; k < n2; ++k) {
      const ulonglong2 qq = ep2[k];
      const float p0 = xt[(int)(qq.x & 0xFFFF) * 64 + lane];
      const float p1 = xt[(int)(qq.y & 0xFFFF) * 64 + lane];
      a0 = fmaf(__uint_as_float((uint32_t)(qq.x >> 32)), p0, a0);
      a1 = fmaf(__uint_as_float((uint32_t)(qq.y >> 32)), p1, a1);
    }
    tile[w * 4 + q][lane] = (a0 + a1) + (a2 + a3);
  }
  __syncthreads();
  // coalesced write-out: out[b][r0+rl]
  #pragma unroll
  for (int pp = 0; pp < (BROWS * 64) / 256; ++pp) {
    const int idx = pp * 256 + t;
    const int bb = idx >> 4;
    const int rl = idx & (BROWS - 1);
    out[(size_t)bb * N_NEUR + r0 + rl] = tile[rl][bb];
  }
}

extern "C" void kernel_launch(void* const* d_in, const int* in_sizes, int n_in,
                              void* d_out, int out_size, void* d_ws, size_t ws_size,
                              hipStream_t stream) {
  const float* x    = (const float*)d_in[0];
  const float* vals = (const float*)d_in[1];
  const int*   rows = (const int*)d_in[2];
  float* out = (float*)d_out;

  char* ws = (char*)d_ws;
  float*    xt     = (float*)   (ws + 0);
  int*      bcnt   = (int*)     (ws + 16777216);
  int*      boffs  = (int*)     (ws + 16793600);
  int*      gcur   = (int*)     (ws + 16809984);
  uint64_t* csr1   = (uint64_t*)(ws + 16826368);
  uint64_t* csr2   = (uint64_t*)(ws + 34160640);
  int*      rowoff = (int*)     (ws + 52019200);
  int*      rowcnt = (int*)     (ws + 52281344);

  hipMemsetAsync(bcnt, 0, NBUK * sizeof(int), stream);
  k_front<<<1024 + NBLK_E, 256, 0, stream>>>(x, xt, rows, bcnt);
  k_bscan<<<1, 256, 0, stream>>>(bcnt, boffs, gcur);
  k_bin<<<NBLK_E, 256, 0, stream>>>(rows, vals, gcur, csr1);
  k_bin2<<<NBUK, 256, 0, stream>>>(bcnt, boffs, csr1, csr2, rowoff, rowcnt);
  k_gather<<<NBUK, 256, 0, stream>>>(xt, rowoff, rowcnt, csr2, out);
}